// Round 4
// baseline (17.702 us; speedup 1.0000x reference)
//
#include <hip/hip_runtime.h>
#include <hip/hip_bf16.h>

// Shapes (fixed by the reference):
//   input:       [B=32, S=2048, H=1024] float32
//   number_mask: [B=32, S=2048] int
//   max_number:  scalar 20 -> J = 20 labels (1..20)
//   output:      [B, J, 2H] float32
#define B_DIM 32
#define S_DIM 2048
#define H_DIM 1024
#define J_DIM 20

// One block of 256 per (b, j). Scan mask row (2 x int4 per thread) for
// first/last occurrence of label j+1, single-barrier block reduce, then
// each thread moves two float4s (first-row half + last-row half).
__global__ __launch_bounds__(256) void aware_fused_kernel(
        const float* __restrict__ in,
        const int* __restrict__ mask,
        float* __restrict__ out) {
    const int bj    = blockIdx.x;        // b * J + j
    const int b     = bj / J_DIM;
    const int label = bj - b * J_DIM + 1;
    const int t     = threadIdx.x;       // 256 threads = 4 waves

    // --- scan: two int4 loads per thread cover all 2048 entries ---
    const int4* m4 = reinterpret_cast<const int4*>(mask + (size_t)b * S_DIM);
    const int4 va  = m4[t];
    const int4 vb  = m4[t + 256];
    int lmin = S_DIM;
    int lmax = -1;
    {
        const int sa = t * 4;
        if (va.x == label) { lmin = min(lmin, sa);     lmax = max(lmax, sa);     }
        if (va.y == label) { lmin = min(lmin, sa + 1); lmax = max(lmax, sa + 1); }
        if (va.z == label) { lmin = min(lmin, sa + 2); lmax = max(lmax, sa + 2); }
        if (va.w == label) { lmin = min(lmin, sa + 3); lmax = max(lmax, sa + 3); }
        const int sb = (t + 256) * 4;
        if (vb.x == label) { lmin = min(lmin, sb);     lmax = max(lmax, sb);     }
        if (vb.y == label) { lmin = min(lmin, sb + 1); lmax = max(lmax, sb + 1); }
        if (vb.z == label) { lmin = min(lmin, sb + 2); lmax = max(lmax, sb + 2); }
        if (vb.w == label) { lmin = min(lmin, sb + 3); lmax = max(lmax, sb + 3); }
    }

    // --- wave (64-lane) reduce ---
    #pragma unroll
    for (int off = 32; off > 0; off >>= 1) {
        lmin = min(lmin, __shfl_down(lmin, off, 64));
        lmax = max(lmax, __shfl_down(lmax, off, 64));
    }

    // --- cross-wave combine: one barrier, broadcast reads ---
    __shared__ int swf[4], swl[4];
    if ((t & 63) == 0) {
        swf[t >> 6] = lmin;
        swl[t >> 6] = lmax;
    }
    __syncthreads();
    int f = swf[0], l = swl[0];
    #pragma unroll
    for (int w = 1; w < 4; ++w) {
        f = min(f, swf[w]);
        l = max(l, swl[w]);
    }
    const bool exists = (f < S_DIM);

    // --- gather: two float4 per thread ---
    float4* o = reinterpret_cast<float4*>(out + (size_t)bj * (2 * H_DIM));
    if (exists) {
        const float4* src_f = reinterpret_cast<const float4*>(
            in + ((size_t)b * S_DIM + f) * H_DIM);
        const float4* src_l = reinterpret_cast<const float4*>(
            in + ((size_t)b * S_DIM + l) * H_DIM);
        o[t]             = src_f[t];
        o[t + H_DIM / 4] = src_l[t];
    } else {
        float4 z; z.x = 0.f; z.y = 0.f; z.z = 0.f; z.w = 0.f;
        o[t]             = z;
        o[t + H_DIM / 4] = z;
    }
}

extern "C" void kernel_launch(void* const* d_in, const int* in_sizes, int n_in,
                              void* d_out, int out_size, void* d_ws, size_t ws_size,
                              hipStream_t stream) {
    const float* input = (const float*)d_in[0];
    const int*   mask  = (const int*)d_in[1];
    float*       out   = (float*)d_out;

    aware_fused_kernel<<<B_DIM * J_DIM, 256, 0, stream>>>(input, mask, out);
}

// Round 5
// 17.460 us; speedup vs baseline: 1.0139x; 1.0139x over previous
//
#include <hip/hip_runtime.h>
#include <hip/hip_bf16.h>

// Shapes (fixed by the reference):
//   input:       [B=32, S=2048, H=1024] float32
//   number_mask: [B=32, S=2048] int
//   max_number:  scalar 20 -> J = 20 labels (1..20)
//   output:      [B, J, 2H] float32
#define B_DIM 32
#define S_DIM 2048
#define H_DIM 1024
#define J_DIM 20

// One block of 256 per (b, j). Every wave redundantly scans the whole mask
// row (lane covers 32 contiguous entries = 8 int4), so first/last resolve
// with a single ballot + 2 shfl — no LDS, no __syncthreads. Then each
// thread moves two float4s (first-row half + last-row half).
__global__ __launch_bounds__(256) void aware_fused_kernel(
        const float* __restrict__ in,
        const int* __restrict__ mask,
        float* __restrict__ out) {
    const int bj    = blockIdx.x;        // b * J + j
    const int b     = bj / J_DIM;
    const int label = bj - b * J_DIM + 1;
    const int t     = threadIdx.x;       // 256 threads = 4 waves
    const int lane  = t & 63;

    // --- scan: each wave covers the full row; lane -> entries [lane*32, lane*32+32) ---
    const int4* m4 = reinterpret_cast<const int4*>(mask + (size_t)b * S_DIM);
    int lmin = S_DIM;
    int lmax = -1;
    #pragma unroll
    for (int k = 0; k < 8; ++k) {
        const int i4 = lane * 8 + k;     // int4 index
        const int4 v = m4[i4];
        const int  s = i4 * 4;
        if (v.x == label) { lmin = min(lmin, s);     lmax = max(lmax, s);     }
        if (v.y == label) { lmin = min(lmin, s + 1); lmax = max(lmax, s + 1); }
        if (v.z == label) { lmin = min(lmin, s + 2); lmax = max(lmax, s + 2); }
        if (v.w == label) { lmin = min(lmin, s + 3); lmax = max(lmax, s + 3); }
    }

    // --- resolve: lanes are ordered chunks, so ballot gives global min/max lanes ---
    const unsigned long long bal = __ballot(lmax >= 0);
    const bool exists = (bal != 0ull);
    int f = 0, l = 0;
    if (exists) {
        const int firstlane = __builtin_ctzll(bal);
        const int lastlane  = 63 - __builtin_clzll(bal);
        f = __shfl(lmin, firstlane, 64);
        l = __shfl(lmax, lastlane, 64);
    }

    // --- gather: two float4 per thread ---
    float4* o = reinterpret_cast<float4*>(out + (size_t)bj * (2 * H_DIM));
    if (exists) {
        const float4* src_f = reinterpret_cast<const float4*>(
            in + ((size_t)b * S_DIM + f) * H_DIM);
        const float4* src_l = reinterpret_cast<const float4*>(
            in + ((size_t)b * S_DIM + l) * H_DIM);
        o[t]             = src_f[t];
        o[t + H_DIM / 4] = src_l[t];
    } else {
        float4 z; z.x = 0.f; z.y = 0.f; z.z = 0.f; z.w = 0.f;
        o[t]             = z;
        o[t + H_DIM / 4] = z;
    }
}

extern "C" void kernel_launch(void* const* d_in, const int* in_sizes, int n_in,
                              void* d_out, int out_size, void* d_ws, size_t ws_size,
                              hipStream_t stream) {
    const float* input = (const float*)d_in[0];
    const int*   mask  = (const int*)d_in[1];
    float*       out   = (float*)d_out;

    aware_fused_kernel<<<B_DIM * J_DIM, 256, 0, stream>>>(input, mask, out);
}

// Round 6
// 9.927 us; speedup vs baseline: 1.7833x; 1.7589x over previous
//
#include <hip/hip_runtime.h>
#include <hip/hip_bf16.h>

// Shapes (fixed by the reference):
//   input:       [B=32, S=2048, H=1024] float32
//   number_mask: [B=32, S=2048] int
//   max_number:  scalar 20 -> J = 20 labels (1..20)
//   output:      [B, J, 2H] float32
#define B_DIM 32
#define S_DIM 2048
#define H_DIM 1024
#define J_DIM 20

// One block per (b, j). Scan mask row for label j+1 (first/last position),
// then copy input[b, first, :] -> out[b,j,0:H], input[b, last, :] -> out[b,j,H:2H].
// Zeros when the label is absent (d_out is poisoned, must write explicitly).
// NOTE: this is the round-2 source verbatim — A/A re-measurement to establish
// the cross-round noise band (R3/R4/R5 structural "regressions" are suspected
// to be environment noise, not kernel effects).
__global__ __launch_bounds__(256) void aware_fused_kernel(
        const float* __restrict__ in,
        const int* __restrict__ mask,
        float* __restrict__ out) {
    const int bj    = blockIdx.x;        // b * J + j
    const int b     = bj / J_DIM;
    const int label = bj - b * J_DIM + 1;
    const int t     = threadIdx.x;       // 256 threads

    // --- scan mask row for first/last occurrence of `label` ---
    int lmin = S_DIM;
    int lmax = -1;
    const int* m = mask + (size_t)b * S_DIM;
    #pragma unroll
    for (int k = 0; k < S_DIM / 256; ++k) {
        int s = t + k * 256;
        int v = m[s];
        if (v == label) {
            lmin = min(lmin, s);
            lmax = max(lmax, s);
        }
    }
    // wave (64-lane) butterfly reduce
    #pragma unroll
    for (int off = 32; off > 0; off >>= 1) {
        lmin = min(lmin, __shfl_down(lmin, off, 64));
        lmax = max(lmax, __shfl_down(lmax, off, 64));
    }
    // combine 4 waves via LDS
    __shared__ int sf, sl;
    if (t == 0) { sf = S_DIM; sl = -1; }
    __syncthreads();
    if ((t & 63) == 0) {
        atomicMin(&sf, lmin);
        atomicMax(&sl, lmax);
    }
    __syncthreads();
    const int f = sf;
    const int l = sl;
    const bool exists = (f < S_DIM);

    // --- gather: H/4 = 256 float4 per half, one per thread ---
    float4* o = reinterpret_cast<float4*>(out + (size_t)bj * (2 * H_DIM));
    if (exists) {
        const float4* src_f = reinterpret_cast<const float4*>(
            in + ((size_t)b * S_DIM + f) * H_DIM);
        const float4* src_l = reinterpret_cast<const float4*>(
            in + ((size_t)b * S_DIM + l) * H_DIM);
        o[t]             = src_f[t];
        o[t + H_DIM / 4] = src_l[t];
    } else {
        float4 z; z.x = 0.f; z.y = 0.f; z.z = 0.f; z.w = 0.f;
        o[t]             = z;
        o[t + H_DIM / 4] = z;
    }
}

extern "C" void kernel_launch(void* const* d_in, const int* in_sizes, int n_in,
                              void* d_out, int out_size, void* d_ws, size_t ws_size,
                              hipStream_t stream) {
    const float* input = (const float*)d_in[0];
    const int*   mask  = (const int*)d_in[1];
    float*       out   = (float*)d_out;

    aware_fused_kernel<<<B_DIM * J_DIM, 256, 0, stream>>>(input, mask, out);
}